// Round 4
// baseline (280.855 us; speedup 1.0000x reference)
//
#include <hip/hip_runtime.h>

typedef __bf16 bf16_t;
typedef __bf16 bf16x8 __attribute__((ext_vector_type(8)));
typedef __bf16 bf16x4v __attribute__((ext_vector_type(4)));
typedef float f32x4 __attribute__((ext_vector_type(4)));

#define MFMA16(a, b, c) __builtin_amdgcn_mfma_f32_16x16x32_bf16((a), (b), (c), 0, 0, 0)

// problem constants
static constexpr int B_ = 8, N_ = 1024, F_ = 512, H_ = 8;
static constexpr int M_ = B_ * N_;  // 8192

__device__ __forceinline__ void gl_lds16(const bf16_t* gsrc, bf16_t* ldst) {
  // async global->LDS, 16B/lane; LDS dest = wave-uniform base + lane*16
  __builtin_amdgcn_global_load_lds(
      (const __attribute__((address_space(1))) void*)gsrc,
      (__attribute__((address_space(3))) void*)ldst, 16, 0, 0);
}

// ---------------- prep kernels ----------------
__global__ __launch_bounds__(256) void k_cast_bf16(const float* __restrict__ in,
                                                   bf16_t* __restrict__ out, int n4) {
  int i = blockIdx.x * 256 + threadIdx.x;
  if (i >= n4) return;
  float4 v = ((const float4*)in)[i];
  bf16x4v o;
  o[0] = (bf16_t)v.x; o[1] = (bf16_t)v.y; o[2] = (bf16_t)v.z; o[3] = (bf16_t)v.w;
  ((bf16x4v*)out)[i] = o;
}

// W (K,N) f32 row-major -> Wt (N,K) bf16
__global__ void k_transpose_w(const float* __restrict__ W, bf16_t* __restrict__ Wt,
                              int K, int N) {
  __shared__ float t[32][33];
  int kb = blockIdx.y * 32, cb = blockIdx.x * 32;
  int tx = threadIdx.x, ty = threadIdx.y;  // (32,8)
#pragma unroll
  for (int i = 0; i < 4; ++i)
    t[ty * 4 + i][tx] = W[(long)(kb + ty * 4 + i) * N + cb + tx];
  __syncthreads();
#pragma unroll
  for (int i = 0; i < 4; ++i)
    Wt[(long)(cb + ty * 4 + i) * K + kb + tx] = (bf16_t)t[tx][ty * 4 + i];
}

// per b: in[(b*1024+n)*inStride + colOff + c] (c<512) -> out[(b*512+c)*1024 + n]
__global__ void k_transpose_v(const bf16_t* __restrict__ in, bf16_t* __restrict__ out,
                              int inStride, int colOff) {
  __shared__ bf16_t t[32][33];
  int b = blockIdx.z;
  int cb = blockIdx.x * 32, nb = blockIdx.y * 32;
  int tx = threadIdx.x, ty = threadIdx.y;  // (32,8)
#pragma unroll
  for (int i = 0; i < 4; ++i)
    t[ty * 4 + i][tx] = in[((long)b * 1024 + nb + ty * 4 + i) * inStride + colOff + cb + tx];
  __syncthreads();
#pragma unroll
  for (int i = 0; i < 4; ++i)
    out[((long)b * 512 + cb + ty * 4 + i) * 1024 + nb + tx] = t[tx][ty * 4 + i];
}

__global__ void k_concat3(const float* a, const float* b, const float* c, float* dst) {
  int i = blockIdx.x * 256 + threadIdx.x;
  if (i >= 1536) return;
  dst[i] = i < 512 ? a[i] : (i < 1024 ? b[i - 512] : c[i - 1024]);
}

// reduce dist-MLP to 8 gelu coeffs: meanDW(d) = dc[24] + sum_j gelu(d*dc[j]+dc[8+j])*dc[16+j]
__global__ void k_dcoef(const float* d1w, const float* d1b, const float* d2w,
                        const float* d2b, float* dc) {
  int j = threadIdx.x;
  if (j < 8) {
    dc[j] = d1w[j];
    dc[8 + j] = d1b[j];
    float s = 0.f;
    for (int h = 0; h < 8; ++h) s += d2w[j * 8 + h];
    dc[16 + j] = s * 0.125f;
  }
  if (j == 0) {
    float s = 0.f;
    for (int h = 0; h < 8; ++h) s += d2b[h];
    dc[24] = s * 0.125f;
  }
}

__device__ __forceinline__ float gelu_tanh(float u) {
  // jax.nn.gelu approximate=True
  float g = 0.7978845608028654f * fmaf(0.044715f * u * u, u, u);
  float e = __expf(2.f * g);
  float t = 1.f - 2.f / (e + 1.f);
  return 0.5f * u * (1.f + t);
}

// LUT over d in [0,16), 4096 bins, value at bin center
__global__ void k_build_lut(const float* __restrict__ dc, float* __restrict__ lut) {
  int i = blockIdx.x * 256 + threadIdx.x;
  if (i >= 4096) return;
  float d = (i + 0.5f) * (16.f / 4096.f);
  float s = dc[24];
#pragma unroll
  for (int j = 0; j < 8; ++j)
    s = fmaf(gelu_tanh(fmaf(d, dc[j], dc[8 + j])), dc[16 + j], s);
  lut[i] = s;
}

// ---------------- 128x128 bf16 GEMM, BK=64, global_load_lds (m97 structure) -----
struct GemmArgs {
  const bf16_t* A; const bf16_t* Bt;
  const float* bias; const float* addSrc;
  const float* coords; const float* lut;
  float* outF; bf16_t* outB;
  long strideAb; long strideBb;
  int lda, ldb, K, ldout;
  float scale;
};

template <int DIST>
__global__ __launch_bounds__(256) void k_gemm128(GemmArgs g) {
  __shared__ alignas(16) bf16_t As[128][64];
  __shared__ alignas(16) bf16_t Bs[128][64];
  __shared__ float Lut[DIST ? 4096 : 4];
  const int tid = threadIdx.x;
  const int w = tid >> 6, lane = tid & 63;
  const int lr = lane & 15, lg = lane >> 4;
  const int wr = w >> 1, wc = w & 1;
  const int mBase = blockIdx.y * 128, cBase = blockIdx.x * 128;
  const int batch = mBase >> 10;  // 128 | 1024, tiles never cross batch

  if constexpr (DIST) {
    const float4* src = (const float4*)g.lut;
    ((float4*)Lut)[tid] = src[tid];
    ((float4*)Lut)[tid + 256] = src[tid + 256];
    ((float4*)Lut)[tid + 512] = src[tid + 512];
    ((float4*)Lut)[tid + 768] = src[tid + 768];
  }

  // staging: each wave owns 32 rows of As and Bs; 1 issue = 8 rows (64 lanes x 16B)
  const int srow = lane >> 3;           // 0..7
  const int scol = (lane & 7) * 8;      // element offset within row
  const bf16_t* Ag = g.A + (long)batch * g.strideAb +
                     (long)((mBase & 1023) + w * 32 + srow) * g.lda + scol;
  const bf16_t* Bg = g.Bt + (long)batch * g.strideBb +
                     (long)(cBase + w * 32 + srow) * g.ldb + scol;
  bf16_t* Al = &As[w * 32][0];
  bf16_t* Bl = &Bs[w * 32][0];

  f32x4 zero = {0.f, 0.f, 0.f, 0.f};
  f32x4 acc[4][4];
#pragma unroll
  for (int i = 0; i < 4; ++i)
#pragma unroll
    for (int j = 0; j < 4; ++j) acc[i][j] = zero;

  for (int k0 = 0; k0 < g.K; k0 += 64) {
#pragma unroll
    for (int is = 0; is < 4; ++is) {
      gl_lds16(Ag + (long)(is * 8) * g.lda + k0, Al + is * 8 * 64);
      gl_lds16(Bg + (long)(is * 8) * g.ldb + k0, Bl + is * 8 * 64);
    }
    __syncthreads();  // drains vmcnt(0): tile staged
#pragma unroll
    for (int ks = 0; ks < 2; ++ks) {
      bf16x8 a[4], b[4];
#pragma unroll
      for (int i = 0; i < 4; ++i) {
        a[i] = *(const bf16x8*)(&As[wr * 64 + i * 16 + lr][ks * 32 + lg * 8]);
        b[i] = *(const bf16x8*)(&Bs[wc * 64 + i * 16 + lr][ks * 32 + lg * 8]);
      }
#pragma unroll
      for (int mf = 0; mf < 4; ++mf)
#pragma unroll
        for (int nf = 0; nf < 4; ++nf)
          acc[mf][nf] = MFMA16(a[mf], b[nf], acc[mf][nf]);
    }
    __syncthreads();  // all reads done before next overwrite
  }

  // ---- epilogue ----
  const int c0 = cBase + wc * 64;
  float bias4[4];
#pragma unroll
  for (int nf = 0; nf < 4; ++nf)
    bias4[nf] = g.bias ? g.bias[c0 + nf * 16 + lr] : 0.f;
  float ckx[4], cky[4], ckz[4];
  if constexpr (DIST) {
#pragma unroll
    for (int nf = 0; nf < 4; ++nf) {
      const float* ck = g.coords + ((long)batch * 1024 + c0 + nf * 16 + lr) * 3;
      ckx[nf] = ck[0]; cky[nf] = ck[1]; ckz[nf] = ck[2];
    }
  }
#pragma unroll
  for (int mf = 0; mf < 4; ++mf) {
    const int r0 = mBase + wr * 64 + mf * 16 + lg * 4;
    float cqx[4], cqy[4], cqz[4];
    if constexpr (DIST) {
#pragma unroll
      for (int rg = 0; rg < 4; ++rg) {
        const float* cq = g.coords + ((long)batch * 1024 + ((r0 + rg) & 1023)) * 3;
        cqx[rg] = cq[0]; cqy[rg] = cq[1]; cqz[rg] = cq[2];
      }
    }
#pragma unroll
    for (int nf = 0; nf < 4; ++nf) {
      const int c = c0 + nf * 16 + lr;
#pragma unroll
      for (int rg = 0; rg < 4; ++rg) {
        const int r = r0 + rg;
        float v = acc[mf][nf][rg] * g.scale + bias4[nf];
        if (g.addSrc) v += g.addSrc[(long)r * g.ldout + c];
        if constexpr (DIST) {
          float dx = cqx[rg] - ckx[nf], dy = cqy[rg] - cky[nf], dz = cqz[rg] - ckz[nf];
          float d = sqrtf(fmaxf(dx * dx + dy * dy + dz * dz, 1e-12f));
          int idx = (int)(d * 256.f);
          idx = idx > 4095 ? 4095 : idx;
          v += Lut[idx];
        }
        const long oi = (long)r * g.ldout + c;
        if (g.outF) g.outF[oi] = v;
        if (g.outB) g.outB[oi] = (bf16_t)v;
      }
    }
  }
}

// ---------------- row softmax (1024 cols, fp32 in -> bf16 out) ----------------
__global__ __launch_bounds__(256) void k_softmax_rows(const float* __restrict__ S,
                                                      bf16_t* __restrict__ P) {
  const long row = blockIdx.x;
  const float* s = S + row * 1024;
  const int tid = threadIdx.x;
  float4 v = ((const float4*)s)[tid];
  float mx = fmaxf(fmaxf(v.x, v.y), fmaxf(v.z, v.w));
#pragma unroll
  for (int d = 1; d < 64; d <<= 1) mx = fmaxf(mx, __shfl_xor(mx, d));
  __shared__ float redM[4], redS[4];
  if ((tid & 63) == 0) redM[tid >> 6] = mx;
  __syncthreads();
  mx = fmaxf(fmaxf(redM[0], redM[1]), fmaxf(redM[2], redM[3]));
  float e0 = __expf(v.x - mx), e1 = __expf(v.y - mx);
  float e2 = __expf(v.z - mx), e3 = __expf(v.w - mx);
  float sm = e0 + e1 + e2 + e3;
#pragma unroll
  for (int d = 1; d < 64; d <<= 1) sm += __shfl_xor(sm, d);
  if ((tid & 63) == 0) redS[tid >> 6] = sm;
  __syncthreads();
  sm = redS[0] + redS[1] + redS[2] + redS[3];
  float inv = 1.f / sm;
  bf16x4v o;
  o[0] = (bf16_t)(e0 * inv); o[1] = (bf16_t)(e1 * inv);
  o[2] = (bf16_t)(e2 * inv); o[3] = (bf16_t)(e3 * inv);
  ((bf16x4v*)(P + row * 1024))[tid] = o;
}

// -------- feature-branch flash attention, split-K (no online max needed) --------
// grid (8, B*H, 2); block z handles keys [z*512, z*512+512).
// Writes UNNORMALIZED f32 O-partials + per-(q,h) l-partials; k_flash_combine
// finishes (O0+O1)/(l0+l1) -> bf16 fatt. Valid because p=exp(s/8) unshifted
// makes the key-sum fully associative.
__global__ __launch_bounds__(256) void k_flash_feat(const bf16_t* __restrict__ QKV,
                                                    const bf16_t* __restrict__ Vt,
                                                    float* __restrict__ Opart,
                                                    float* __restrict__ Lpart) {
  const int wave = threadIdx.x >> 6, lane = threadIdx.x & 63;
  const int lr = lane & 15, lg = (lane >> 4) & 3;
  const int bh = blockIdx.y, b = bh >> 3, h = bh & 7;
  const int z = blockIdx.z;
  const int qbase = blockIdx.x * 128 + wave * 32;
  __shared__ alignas(16) bf16_t Pl[4][2][16][40];

  const bf16_t* Qb = QKV + (long)b * 1024 * 1536 + h * 64;
  const bf16_t* Kb = Qb + 512;
  const bf16_t* Vb = Vt + ((long)b * 512 + h * 64) * 1024;

  bf16x8 q_[2][2];
#pragma unroll
  for (int qf = 0; qf < 2; ++qf)
#pragma unroll
    for (int dh = 0; dh < 2; ++dh)
      q_[qf][dh] = *(const bf16x8*)(Qb + (long)(qbase + qf * 16 + lr) * 1536 + dh * 32 + lg * 8);

  f32x4 zero = {0.f, 0.f, 0.f, 0.f};
  f32x4 oacc[2][4] = {{zero, zero, zero, zero}, {zero, zero, zero, zero}};
  float lsum[2] = {0.f, 0.f};
  constexpr float SCL = 0.18033688011112042f;  // 0.125 * log2(e)

  auto loadK = [&](bf16x8* dst, int kt) {
#pragma unroll
    for (int i = 0; i < 4; ++i)
      dst[i] = *(const bf16x8*)(Kb + (long)(kt + (i >> 1) * 16 + lr) * 1536 + (i & 1) * 32 + lg * 8);
  };
  auto loadV = [&](bf16x8* dst, int kt) {
#pragma unroll
    for (int ct = 0; ct < 4; ++ct)
      dst[ct] = *(const bf16x8*)(Vb + (long)(ct * 16 + lr) * 1024 + kt + lg * 8);
  };

  auto step = [&](bf16x8* curK, bf16x8* curV, bf16x8* nxtK, bf16x8* nxtV, int kt)
      __attribute__((always_inline)) {
    const int kn = (kt + 32) & 1023;
    loadK(nxtK, kn);
    loadV(nxtV, kn);
    f32x4 S[2][2];
#pragma unroll
    for (int qf = 0; qf < 2; ++qf)
#pragma unroll
      for (int kh = 0; kh < 2; ++kh) {
        f32x4 t = MFMA16(curK[kh * 2 + 0], q_[qf][0], zero);
        S[qf][kh] = MFMA16(curK[kh * 2 + 1], q_[qf][1], t);
      }
#pragma unroll
    for (int qf = 0; qf < 2; ++qf)
#pragma unroll
      for (int kh = 0; kh < 2; ++kh) {
        bf16x4v pp;
#pragma unroll
        for (int r = 0; r < 4; ++r) {
          float e = exp2f(S[qf][kh][r] * SCL);
          lsum[qf] += e;
          pp[r] = (bf16_t)e;
        }
        *(bf16x4v*)(&Pl[wave][qf][lr][kh * 16 + lg * 4]) = pp;
      }
    asm volatile("s_waitcnt lgkmcnt(0)" ::: "memory");
    const bf16x8 pa0 = *(const bf16x8*)(&Pl[wave][0][lr][lg * 8]);
    const bf16x8 pa1 = *(const bf16x8*)(&Pl[wave][1][lr][lg * 8]);
#pragma unroll
    for (int ct = 0; ct < 4; ++ct) {
      oacc[0][ct] = MFMA16(pa0, curV[ct], oacc[0][ct]);
      oacc[1][ct] = MFMA16(pa1, curV[ct], oacc[1][ct]);
    }
  };

  bf16x8 kA[4], vA[4], kB[4], vB[4];
  const int kBeg = z * 512;
  loadK(kA, kBeg);
  loadV(vA, kBeg);
  for (int kt = kBeg; kt < kBeg + 512; kt += 64) {
    step(kA, vA, kB, vB, kt);
    step(kB, vB, kA, vA, kt + 32);
  }

  // l partial: after 2 xors every lane holds the sum for q = qbase+qf*16+(lane&15)
#pragma unroll
  for (int qf = 0; qf < 2; ++qf) {
    float l = lsum[qf];
    l += __shfl_xor(l, 16);
    l += __shfl_xor(l, 32);
    lsum[qf] = l;
  }
  if (lg == 0) {
#pragma unroll
    for (int qf = 0; qf < 2; ++qf)
      Lpart[((long)z * M_ + b * 1024 + qbase + qf * 16 + lr) * 8 + h] = lsum[qf];
  }
  // unnormalized O partial (f32)
#pragma unroll
  for (int qf = 0; qf < 2; ++qf)
#pragma unroll
    for (int r = 0; r < 4; ++r) {
      int q = qbase + qf * 16 + lg * 4 + r;
      float* orow = Opart + ((long)z * M_ + b * 1024 + q) * 512 + h * 64;
#pragma unroll
      for (int ct = 0; ct < 4; ++ct)
        orow[ct * 16 + lr] = oacc[qf][ct][r];
    }
}

// combine: fatt = (O0+O1)/(l0+l1), f32 -> bf16
__global__ __launch_bounds__(256) void k_flash_combine(const float* __restrict__ O,
                                                       const float* __restrict__ L,
                                                       bf16_t* __restrict__ fatt) {
  const long i = (long)blockIdx.x * 256 + threadIdx.x;  // over M_*512/4
  const long r = i >> 7;                                // 128 float4 per row
  const int h = (int)((i & 127) >> 4);                  // c4 = (i&127)*4; h = c4/64
  const float l = L[r * 8 + h] + L[((long)M_ + r) * 8 + h];
  const float4 a = ((const float4*)O)[i];
  const float4 b = ((const float4*)O)[i + (long)M_ * 128];
  const float inv = 1.f / l;
  bf16x4v o;
  o[0] = (bf16_t)((a.x + b.x) * inv);
  o[1] = (bf16_t)((a.y + b.y) * inv);
  o[2] = (bf16_t)((a.z + b.z) * inv);
  o[3] = (bf16_t)((a.w + b.w) * inv);
  ((bf16x4v*)fatt)[i] = o;
}

// ---------------- launch ----------------
extern "C" void kernel_launch(void* const* d_in, const int* in_sizes, int n_in,
                              void* d_out, int out_size, void* d_ws, size_t ws_size,
                              hipStream_t stream) {
  const float* features = (const float*)d_in[0];
  const float* geometry = (const float*)d_in[1];
  const float* coords   = (const float*)d_in[2];
  const float* wq = (const float*)d_in[3];  const float* bq = (const float*)d_in[4];
  const float* wk = (const float*)d_in[5];  const float* bk = (const float*)d_in[6];
  const float* wv = (const float*)d_in[7];  const float* bv = (const float*)d_in[8];
  const float* wo = (const float*)d_in[9];  const float* bo = (const float*)d_in[10];
  const float* gq_w = (const float*)d_in[11]; const float* gq_b = (const float*)d_in[12];
  const float* gk_w = (const float*)d_in[13]; const float* gk_b = (const float*)d_in[14];
  const float* gv_w = (const float*)d_in[15]; const float* gv_b = (const float*)d_in[16];
  const float* d1_w = (const float*)d_in[17]; const float* d1_b = (const float*)d_in[18];
  const float* d2_w = (const float*)d_in[19]; const float* d2_b = (const float*)d_in[20];
  const float* op_w = (const float*)d_in[21]; const float* op_b = (const float*)d_in[22];

  // ---- workspace carve ----
  size_t off = 0;
  auto carve = [&](size_t bytes) {
    void* p = (char*)d_ws + off;
    off += (bytes + 255) & ~(size_t)255;
    return p;
  };
  bf16_t* featBF = (bf16_t*)carve((size_t)M_ * F_ * 2);
  bf16_t* geomBF = (bf16_t*)carve((size_t)M_ * 128 * 2);
  bf16_t* WqkvT  = (bf16_t*)carve((size_t)1536 * 512 * 2);
  bf16_t* GqkvT  = (bf16_t*)carve((size_t)1536 * 128 * 2);
  bf16_t* WoT    = (bf16_t*)carve((size_t)512 * 512 * 2);
  bf16_t* OpT    = (bf16_t*)carve((size_t)512 * 512 * 2);
  float*  bqkv   = (float*)carve(1536 * 4);
  float*  gqkvb  = (float*)carve(1536 * 4);
  float*  dcoef  = (float*)carve(32 * 4);
  float*  dlut   = (float*)carve(4096 * 4);
  float*  lpart  = (float*)carve((size_t)2 * M_ * 8 * 4);      // 0.5 MB
  bf16_t* QKV    = (bf16_t*)carve((size_t)M_ * 1536 * 2);
  bf16_t* GQKV   = (bf16_t*)carve((size_t)M_ * 1536 * 2);
  bf16_t* Vt     = (bf16_t*)carve((size_t)B_ * 512 * 1024 * 2);
  bf16_t* GVt    = (bf16_t*)carve((size_t)B_ * 512 * 1024 * 2);
  float*  gsc    = (float*)carve((size_t)M_ * 1024 * 4);       // 32 MB; reused as Opart
  bf16_t* gattn  = (bf16_t*)carve((size_t)M_ * 1024 * 2);
  bf16_t* fatt   = (bf16_t*)carve((size_t)M_ * 512 * 2);
  float*  combF  = (float*)carve((size_t)M_ * 512 * 4);
  bf16_t* combB  = (bf16_t*)carve((size_t)M_ * 512 * 2);
  if (off > ws_size) return;
  float* opart = gsc;  // gsc is dead after k_softmax_rows; exactly 2*M_*512 floats

  dim3 tb(32, 8);
  k_cast_bf16<<<(M_ * F_ / 4 + 255) / 256, 256, 0, stream>>>(features, featBF, M_ * F_ / 4);
  k_cast_bf16<<<(M_ * 128 / 4 + 255) / 256, 256, 0, stream>>>(geometry, geomBF, M_ * 128 / 4);
  k_transpose_w<<<dim3(16, 16), tb, 0, stream>>>(wq, WqkvT, 512, 512);
  k_transpose_w<<<dim3(16, 16), tb, 0, stream>>>(wk, WqkvT + 512 * 512, 512, 512);
  k_transpose_w<<<dim3(16, 16), tb, 0, stream>>>(wv, WqkvT + 1024 * 512, 512, 512);
  k_transpose_w<<<dim3(16, 4), tb, 0, stream>>>(gq_w, GqkvT, 128, 512);
  k_transpose_w<<<dim3(16, 4), tb, 0, stream>>>(gk_w, GqkvT + 512 * 128, 128, 512);
  k_transpose_w<<<dim3(16, 4), tb, 0, stream>>>(gv_w, GqkvT + 1024 * 128, 128, 512);
  k_transpose_w<<<dim3(16, 16), tb, 0, stream>>>(wo, WoT, 512, 512);
  k_transpose_w<<<dim3(16, 16), tb, 0, stream>>>(op_w, OpT, 512, 512);
  k_concat3<<<6, 256, 0, stream>>>(bq, bk, bv, bqkv);
  k_concat3<<<6, 256, 0, stream>>>(gq_b, gk_b, gv_b, gqkvb);
  k_dcoef<<<1, 64, 0, stream>>>(d1_w, d1_b, d2_w, d2_b, dcoef);
  k_build_lut<<<16, 256, 0, stream>>>(dcoef, dlut);

  auto mk = [](const bf16_t* A, long sAb, int lda, const bf16_t* Bt, long sBb, int ldb,
               int K, const float* bias, const float* addSrc, float* outF, bf16_t* outB,
               int ldout, float scale, const float* coords, const float* lut) {
    GemmArgs g;
    g.A = A; g.Bt = Bt; g.bias = bias; g.addSrc = addSrc;
    g.coords = coords; g.lut = lut; g.outF = outF; g.outB = outB;
    g.strideAb = sAb; g.strideBb = sBb; g.lda = lda; g.ldb = ldb;
    g.K = K; g.ldout = ldout; g.scale = scale;
    return g;
  };

  // 1) QKV = features @ [wq|wk|wv] + b
  k_gemm128<0><<<dim3(12, 64), 256, 0, stream>>>(
      mk(featBF, (long)1024 * 512, 512, WqkvT, 0, 512, 512,
         bqkv, nullptr, nullptr, QKV, 1536, 1.f, nullptr, nullptr));
  // 2) GQKV = geometry @ [gq|gk|gv] + b
  k_gemm128<0><<<dim3(12, 64), 256, 0, stream>>>(
      mk(geomBF, (long)1024 * 128, 128, GqkvT, 0, 128, 128,
         gqkvb, nullptr, nullptr, GQKV, 1536, 1.f, nullptr, nullptr));
  // 3) V, GV -> (B, 512, N)
  k_transpose_v<<<dim3(16, 32, 8), tb, 0, stream>>>(QKV, Vt, 1536, 1024);
  k_transpose_v<<<dim3(16, 32, 8), tb, 0, stream>>>(GQKV, GVt, 1536, 1024);
  // 4) g-scores = GQ.GK^T/8 + LUT(dist)
  k_gemm128<1><<<dim3(8, 64), 256, 0, stream>>>(
      mk(GQKV, (long)1024 * 1536, 1536, GQKV + 512, (long)1024 * 1536, 1536, 512,
         nullptr, nullptr, gsc, nullptr, 1024, 0.125f, coords, dlut));
  // 5) g_attn = softmax(g-scores)  [gsc dead after this]
  k_softmax_rows<<<8192, 256, 0, stream>>>(gsc, gattn);
  // 6) feature flash attention, split-K=2, partials into gsc buffer
  k_flash_feat<<<dim3(8, 64, 2), 256, 0, stream>>>(QKV, Vt, opart, lpart);
  k_flash_combine<<<(int)((long)M_ * 128 / 256), 256, 0, stream>>>(opart, lpart, fatt);
  // 7) combF = fatt @ wo + bo
  k_gemm128<0><<<dim3(4, 64), 256, 0, stream>>>(
      mk(fatt, (long)1024 * 512, 512, WoT, 0, 512, 512,
         bo, nullptr, combF, nullptr, 512, 1.f, nullptr, nullptr));
  // 8) combB = combF + g_attn @ GV
  k_gemm128<0><<<dim3(4, 64), 256, 0, stream>>>(
      mk(gattn, (long)1024 * 1024, 1024, GVt, (long)512 * 1024, 1024, 1024,
         nullptr, combF, nullptr, combB, 512, 1.f, nullptr, nullptr));
  // 9) out = combB @ op_w + op_b
  k_gemm128<0><<<dim3(4, 64), 256, 0, stream>>>(
      mk(combB, (long)1024 * 512, 512, OpT, 0, 512, 512,
         op_b, nullptr, (float*)d_out, nullptr, 512, 1.f, nullptr, nullptr));
}

// Round 5
// 245.404 us; speedup vs baseline: 1.1445x; 1.1445x over previous
//
#include <hip/hip_runtime.h>

typedef __bf16 bf16_t;
typedef __bf16 bf16x8 __attribute__((ext_vector_type(8)));
typedef __bf16 bf16x4v __attribute__((ext_vector_type(4)));
typedef float f32x4 __attribute__((ext_vector_type(4)));

#define MFMA16(a, b, c) __builtin_amdgcn_mfma_f32_16x16x32_bf16((a), (b), (c), 0, 0, 0)

// problem constants
static constexpr int B_ = 8, N_ = 1024, F_ = 512, H_ = 8;
static constexpr int M_ = B_ * N_;  // 8192

__device__ __forceinline__ void gl_lds16(const bf16_t* gsrc, bf16_t* ldst) {
  // async global->LDS, 16B/lane; LDS dest = wave-uniform base + lane*16
  __builtin_amdgcn_global_load_lds(
      (const __attribute__((address_space(1))) void*)gsrc,
      (__attribute__((address_space(3))) void*)ldst, 16, 0, 0);
}

// ---------------- prep kernels ----------------
__global__ __launch_bounds__(256) void k_cast_bf16(const float* __restrict__ in,
                                                   bf16_t* __restrict__ out, int n4) {
  int i = blockIdx.x * 256 + threadIdx.x;
  if (i >= n4) return;
  float4 v = ((const float4*)in)[i];
  bf16x4v o;
  o[0] = (bf16_t)v.x; o[1] = (bf16_t)v.y; o[2] = (bf16_t)v.z; o[3] = (bf16_t)v.w;
  ((bf16x4v*)out)[i] = o;
}

// W (K,N) f32 row-major -> Wt (N,K) bf16
__global__ void k_transpose_w(const float* __restrict__ W, bf16_t* __restrict__ Wt,
                              int K, int N) {
  __shared__ float t[32][33];
  int kb = blockIdx.y * 32, cb = blockIdx.x * 32;
  int tx = threadIdx.x, ty = threadIdx.y;  // (32,8)
#pragma unroll
  for (int i = 0; i < 4; ++i)
    t[ty * 4 + i][tx] = W[(long)(kb + ty * 4 + i) * N + cb + tx];
  __syncthreads();
#pragma unroll
  for (int i = 0; i < 4; ++i)
    Wt[(long)(cb + ty * 4 + i) * K + kb + tx] = (bf16_t)t[tx][ty * 4 + i];
}

// per b: in[(b*1024+n)*inStride + colOff + c] (c<512) -> out[(b*512+c)*1024 + n]
__global__ void k_transpose_v(const bf16_t* __restrict__ in, bf16_t* __restrict__ out,
                              int inStride, int colOff) {
  __shared__ bf16_t t[32][33];
  int b = blockIdx.z;
  int cb = blockIdx.x * 32, nb = blockIdx.y * 32;
  int tx = threadIdx.x, ty = threadIdx.y;  // (32,8)
#pragma unroll
  for (int i = 0; i < 4; ++i)
    t[ty * 4 + i][tx] = in[((long)b * 1024 + nb + ty * 4 + i) * inStride + colOff + cb + tx];
  __syncthreads();
#pragma unroll
  for (int i = 0; i < 4; ++i)
    out[((long)b * 512 + cb + ty * 4 + i) * 1024 + nb + tx] = t[tx][ty * 4 + i];
}

__global__ void k_concat3(const float* a, const float* b, const float* c, float* dst) {
  int i = blockIdx.x * 256 + threadIdx.x;
  if (i >= 1536) return;
  dst[i] = i < 512 ? a[i] : (i < 1024 ? b[i - 512] : c[i - 1024]);
}

// reduce dist-MLP to 8 gelu coeffs: meanDW(d) = dc[24] + sum_j gelu(d*dc[j]+dc[8+j])*dc[16+j]
__global__ void k_dcoef(const float* d1w, const float* d1b, const float* d2w,
                        const float* d2b, float* dc) {
  int j = threadIdx.x;
  if (j < 8) {
    dc[j] = d1w[j];
    dc[8 + j] = d1b[j];
    float s = 0.f;
    for (int h = 0; h < 8; ++h) s += d2w[j * 8 + h];
    dc[16 + j] = s * 0.125f;
  }
  if (j == 0) {
    float s = 0.f;
    for (int h = 0; h < 8; ++h) s += d2b[h];
    dc[24] = s * 0.125f;
  }
}

__device__ __forceinline__ float gelu_tanh(float u) {
  // jax.nn.gelu approximate=True
  float g = 0.7978845608028654f * fmaf(0.044715f * u * u, u, u);
  float e = __expf(2.f * g);
  float t = 1.f - 2.f / (e + 1.f);
  return 0.5f * u * (1.f + t);
}

// LUT over d in [0,16), 4096 bins, value at bin center
__global__ void k_build_lut(const float* __restrict__ dc, float* __restrict__ lut) {
  int i = blockIdx.x * 256 + threadIdx.x;
  if (i >= 4096) return;
  float d = (i + 0.5f) * (16.f / 4096.f);
  float s = dc[24];
#pragma unroll
  for (int j = 0; j < 8; ++j)
    s = fmaf(gelu_tanh(fmaf(d, dc[j], dc[8 + j])), dc[16 + j], s);
  lut[i] = s;
}

// ---------------- 128x128 bf16 GEMM, BK=64, global_load_lds (m97 structure) -----
struct GemmArgs {
  const bf16_t* A; const bf16_t* Bt;
  const float* bias; const float* addSrc;
  const float* coords; const float* lut;
  float* outF; bf16_t* outB;
  long strideAb; long strideBb;
  int lda, ldb, K, ldout;
  float scale;
};

template <int DIST>
__global__ __launch_bounds__(256) void k_gemm128(GemmArgs g) {
  __shared__ alignas(16) bf16_t As[128][64];
  __shared__ alignas(16) bf16_t Bs[128][64];
  __shared__ float Lut[DIST ? 4096 : 4];
  const int tid = threadIdx.x;
  const int w = tid >> 6, lane = tid & 63;
  const int lr = lane & 15, lg = lane >> 4;
  const int wr = w >> 1, wc = w & 1;
  const int mBase = blockIdx.y * 128, cBase = blockIdx.x * 128;
  const int batch = mBase >> 10;  // 128 | 1024, tiles never cross batch

  if constexpr (DIST) {
    const float4* src = (const float4*)g.lut;
    ((float4*)Lut)[tid] = src[tid];
    ((float4*)Lut)[tid + 256] = src[tid + 256];
    ((float4*)Lut)[tid + 512] = src[tid + 512];
    ((float4*)Lut)[tid + 768] = src[tid + 768];
  }

  // staging: each wave owns 32 rows of As and Bs; 1 issue = 8 rows (64 lanes x 16B)
  const int srow = lane >> 3;           // 0..7
  const int scol = (lane & 7) * 8;      // element offset within row
  const bf16_t* Ag = g.A + (long)batch * g.strideAb +
                     (long)((mBase & 1023) + w * 32 + srow) * g.lda + scol;
  const bf16_t* Bg = g.Bt + (long)batch * g.strideBb +
                     (long)(cBase + w * 32 + srow) * g.ldb + scol;
  bf16_t* Al = &As[w * 32][0];
  bf16_t* Bl = &Bs[w * 32][0];

  f32x4 zero = {0.f, 0.f, 0.f, 0.f};
  f32x4 acc[4][4];
#pragma unroll
  for (int i = 0; i < 4; ++i)
#pragma unroll
    for (int j = 0; j < 4; ++j) acc[i][j] = zero;

  for (int k0 = 0; k0 < g.K; k0 += 64) {
#pragma unroll
    for (int is = 0; is < 4; ++is) {
      gl_lds16(Ag + (long)(is * 8) * g.lda + k0, Al + is * 8 * 64);
      gl_lds16(Bg + (long)(is * 8) * g.ldb + k0, Bl + is * 8 * 64);
    }
    __syncthreads();  // drains vmcnt(0): tile staged
#pragma unroll
    for (int ks = 0; ks < 2; ++ks) {
      bf16x8 a[4], b[4];
#pragma unroll
      for (int i = 0; i < 4; ++i) {
        a[i] = *(const bf16x8*)(&As[wr * 64 + i * 16 + lr][ks * 32 + lg * 8]);
        b[i] = *(const bf16x8*)(&Bs[wc * 64 + i * 16 + lr][ks * 32 + lg * 8]);
      }
#pragma unroll
      for (int mf = 0; mf < 4; ++mf)
#pragma unroll
        for (int nf = 0; nf < 4; ++nf)
          acc[mf][nf] = MFMA16(a[mf], b[nf], acc[mf][nf]);
    }
    __syncthreads();  // all reads done before next overwrite
  }

  // ---- epilogue ----
  const int c0 = cBase + wc * 64;
  float bias4[4];
#pragma unroll
  for (int nf = 0; nf < 4; ++nf)
    bias4[nf] = g.bias ? g.bias[c0 + nf * 16 + lr] : 0.f;
  float ckx[4], cky[4], ckz[4];
  if constexpr (DIST) {
#pragma unroll
    for (int nf = 0; nf < 4; ++nf) {
      const float* ck = g.coords + ((long)batch * 1024 + c0 + nf * 16 + lr) * 3;
      ckx[nf] = ck[0]; cky[nf] = ck[1]; ckz[nf] = ck[2];
    }
  }
#pragma unroll
  for (int mf = 0; mf < 4; ++mf) {
    const int r0 = mBase + wr * 64 + mf * 16 + lg * 4;
    float cqx[4], cqy[4], cqz[4];
    if constexpr (DIST) {
#pragma unroll
      for (int rg = 0; rg < 4; ++rg) {
        const float* cq = g.coords + ((long)batch * 1024 + ((r0 + rg) & 1023)) * 3;
        cqx[rg] = cq[0]; cqy[rg] = cq[1]; cqz[rg] = cq[2];
      }
    }
#pragma unroll
    for (int nf = 0; nf < 4; ++nf) {
      const int c = c0 + nf * 16 + lr;
#pragma unroll
      for (int rg = 0; rg < 4; ++rg) {
        const int r = r0 + rg;
        float v = acc[mf][nf][rg] * g.scale + bias4[nf];
        if (g.addSrc) v += g.addSrc[(long)r * g.ldout + c];
        if constexpr (DIST) {
          float dx = cqx[rg] - ckx[nf], dy = cqy[rg] - cky[nf], dz = cqz[rg] - ckz[nf];
          float d = sqrtf(fmaxf(dx * dx + dy * dy + dz * dz, 1e-12f));
          int idx = (int)(d * 256.f);
          idx = idx > 4095 ? 4095 : idx;
          v += Lut[idx];
        }
        const long oi = (long)r * g.ldout + c;
        if (g.outF) g.outF[oi] = v;
        if (g.outB) g.outB[oi] = (bf16_t)v;
      }
    }
  }
}

// ---------------- row softmax (1024 cols, fp32 in -> bf16 out) ----------------
__global__ __launch_bounds__(256) void k_softmax_rows(const float* __restrict__ S,
                                                      bf16_t* __restrict__ P) {
  const long row = blockIdx.x;
  const float* s = S + row * 1024;
  const int tid = threadIdx.x;
  float4 v = ((const float4*)s)[tid];
  float mx = fmaxf(fmaxf(v.x, v.y), fmaxf(v.z, v.w));
#pragma unroll
  for (int d = 1; d < 64; d <<= 1) mx = fmaxf(mx, __shfl_xor(mx, d));
  __shared__ float redM[4], redS[4];
  if ((tid & 63) == 0) redM[tid >> 6] = mx;
  __syncthreads();
  mx = fmaxf(fmaxf(redM[0], redM[1]), fmaxf(redM[2], redM[3]));
  float e0 = __expf(v.x - mx), e1 = __expf(v.y - mx);
  float e2 = __expf(v.z - mx), e3 = __expf(v.w - mx);
  float sm = e0 + e1 + e2 + e3;
#pragma unroll
  for (int d = 1; d < 64; d <<= 1) sm += __shfl_xor(sm, d);
  if ((tid & 63) == 0) redS[tid >> 6] = sm;
  __syncthreads();
  sm = redS[0] + redS[1] + redS[2] + redS[3];
  float inv = 1.f / sm;
  bf16x4v o;
  o[0] = (bf16_t)(e0 * inv); o[1] = (bf16_t)(e1 * inv);
  o[2] = (bf16_t)(e2 * inv); o[3] = (bf16_t)(e3 * inv);
  ((bf16x4v*)(P + row * 1024))[tid] = o;
}

// -------- feature flash attention: block-shared LDS K/V, XOR-swizzled ----------
// grid (16, B*H); 4 waves x 16 q-rows (QBLK=64/block). KV tiles of 64 keys are
// staged once per block via global_load_lds (2-phase dbuf, T3 minimal recipe),
// shared by all waves. LDS reads use byte^=((row&7)<<4) swizzle with the
// inverse swizzle pre-applied to the global SOURCE address (rule #21).
// Swapped QK^T (S^T=mfma(K,Q)) => softmax lane-local; p=exp(s/8) unshifted.
__global__ __launch_bounds__(256) void k_flash_feat(const bf16_t* __restrict__ QKV,
                                                    const bf16_t* __restrict__ Vt,
                                                    bf16_t* __restrict__ fatt) {
  const int wave = threadIdx.x >> 6, lane = threadIdx.x & 63;
  const int lr = lane & 15, lg = (lane >> 4) & 3;
  const int bh = blockIdx.y, b = bh >> 3, h = bh & 7;
  const int qbase = blockIdx.x * 64 + wave * 16;
  __shared__ alignas(16) bf16_t Ks[2][64][64];   // [buf][key][d]     8KB each
  __shared__ alignas(16) bf16_t Vs[2][64][64];   // [buf][d][key]     8KB each
  __shared__ alignas(16) bf16_t Pl[4][16][40];   // per-wave P relayout

  const bf16_t* Qb = QKV + (long)b * 1024 * 1536 + h * 64;
  const bf16_t* Kb = Qb + 512;
  const bf16_t* Vg = Vt + ((long)b * 512 + h * 64) * 1024;

  // Q B-frag: col=q=lr, k=d=dh*32+lg*8+j (held in regs for whole kernel)
  bf16x8 q_[2];
#pragma unroll
  for (int dh = 0; dh < 2; ++dh)
    q_[dh] = *(const bf16x8*)(Qb + (long)(qbase + lr) * 1536 + dh * 32 + lg * 8);

  // staging: wave stages tile rows [wave*16, wave*16+16) for both K and V^T.
  // linear LDS dest; source col pre-swizzled so LDS[row][c] = data[row][c^((row&7)*8)]
  const int srow = lane >> 3;                       // 0..7 (== row&7 of dest row)
  const int scol = (((lane & 7) ^ srow) << 3);      // swizzled source col (elems)
  const bf16_t* KgB = Kb + (long)(wave * 16 + srow) * 1536 + scol;
  const bf16_t* VgB = Vg + (long)(wave * 16 + srow) * 1024 + scol;

  auto stage = [&](int buf, int kt) {
#pragma unroll
    for (int i = 0; i < 2; ++i) {
      gl_lds16(KgB + (long)(kt + i * 8) * 1536, &Ks[buf][wave * 16 + i * 8][0]);
      gl_lds16(VgB + (long)(i * 8) * 1024 + kt, &Vs[buf][wave * 16 + i * 8][0]);
    }
  };

  f32x4 zero = {0.f, 0.f, 0.f, 0.f};
  f32x4 oacc[4] = {zero, zero, zero, zero};
  float lsum = 0.f;
  constexpr float SCL = 0.18033688011112042f;  // 0.125 * log2(e)
  const int swz = (lr & 7) << 4;                // read-side byte swizzle
  char* PlW = (char*)&Pl[wave][0][0];

  stage(0, 0);
  asm volatile("s_waitcnt vmcnt(0)" ::: "memory");
  __syncthreads();

  for (int t = 0; t < 16; ++t) {
    const int cur = t & 1;
    if (t < 15) stage(cur ^ 1, (t + 1) * 64);
    const char* KB = (const char*)&Ks[cur][0][0];
    const char* VB = (const char*)&Vs[cur][0][0];
#pragma unroll
    for (int kk = 0; kk < 2; ++kk) {
      // QK^T: S^T[kh] rows=keys kk*32+kh*16+lg*4+r, col=q=lr
      f32x4 S[2];
      __builtin_amdgcn_s_setprio(1);
#pragma unroll
      for (int kh = 0; kh < 2; ++kh) {
        const int row = kk * 32 + kh * 16 + lr;
        bf16x8 k0 = *(const bf16x8*)(KB + row * 128 + ((lg * 16) ^ swz));
        bf16x8 k1 = *(const bf16x8*)(KB + row * 128 + ((64 + lg * 16) ^ swz));
        f32x4 tt = MFMA16(k0, q_[0], zero);
        S[kh] = MFMA16(k1, q_[1], tt);
      }
      __builtin_amdgcn_s_setprio(0);
      // p = exp(s/8); accumulate l; relayout via per-wave LDS
#pragma unroll
      for (int kh = 0; kh < 2; ++kh) {
        bf16x4v pp;
#pragma unroll
        for (int r = 0; r < 4; ++r) {
          float e = exp2f(S[kh][r] * SCL);
          lsum += e;
          pp[r] = (bf16_t)e;
        }
        *(bf16x4v*)(PlW + lr * 80 + kh * 32 + lg * 8) = pp;
      }
      asm volatile("s_waitcnt lgkmcnt(0)" ::: "memory");
      const bf16x8 pa = *(const bf16x8*)(PlW + lr * 80 + lg * 16);
      __builtin_amdgcn_s_setprio(1);
#pragma unroll
      for (int ct = 0; ct < 4; ++ct) {
        const int vrow = ct * 16 + lr;
        bf16x8 vf = *(const bf16x8*)(VB + vrow * 128 + ((kk * 64 + lg * 16) ^ swz));
        oacc[ct] = MFMA16(pa, vf, oacc[ct]);
      }
      __builtin_amdgcn_s_setprio(0);
    }
    asm volatile("s_waitcnt vmcnt(0)" ::: "memory");
    __syncthreads();
  }

  // finish l: lanes {lr, lr+16, lr+32, lr+48} hold partials of q = qbase+lr
  lsum += __shfl_xor(lsum, 16);
  lsum += __shfl_xor(lsum, 32);
  // oacc rows are q = lg*4+r; fetch that q's l (held at lane lg*4+r)
#pragma unroll
  for (int r = 0; r < 4; ++r) {
    float inv = 1.f / __shfl(lsum, lg * 4 + r, 64);
    int q = qbase + lg * 4 + r;
    bf16_t* orow = fatt + ((long)b * 1024 + q) * 512 + h * 64;
#pragma unroll
    for (int ct = 0; ct < 4; ++ct)
      orow[ct * 16 + lr] = (bf16_t)(oacc[ct][r] * inv);
  }
}

// ---------------- launch ----------------
extern "C" void kernel_launch(void* const* d_in, const int* in_sizes, int n_in,
                              void* d_out, int out_size, void* d_ws, size_t ws_size,
                              hipStream_t stream) {
  const float* features = (const float*)d_in[0];
  const float* geometry = (const float*)d_in[1];
  const float* coords   = (const float*)d_in[2];
  const float* wq = (const float*)d_in[3];  const float* bq = (const float*)d_in[4];
  const float* wk = (const float*)d_in[5];  const float* bk = (const float*)d_in[6];
  const float* wv = (const float*)d_in[7];  const float* bv = (const float*)d_in[8];
  const float* wo = (const float*)d_in[9];  const float* bo = (const float*)d_in[10];
  const float* gq_w = (const float*)d_in[11]; const float* gq_b = (const float*)d_in[12];
  const float* gk_w = (const float*)d_in[13]; const float* gk_b = (const float*)d_in[14];
  const float* gv_w = (const float*)d_in[15]; const float* gv_b = (const float*)d_in[16];
  const float* d1_w = (const float*)d_in[17]; const float* d1_b = (const float*)d_in[18];
  const float* d2_w = (const float*)d_in[19]; const float* d2_b = (const float*)d_in[20];
  const float* op_w = (const float*)d_in[21]; const float* op_b = (const float*)d_in[22];

  // ---- workspace carve ----
  size_t off = 0;
  auto carve = [&](size_t bytes) {
    void* p = (char*)d_ws + off;
    off += (bytes + 255) & ~(size_t)255;
    return p;
  };
  bf16_t* featBF = (bf16_t*)carve((size_t)M_ * F_ * 2);
  bf16_t* geomBF = (bf16_t*)carve((size_t)M_ * 128 * 2);
  bf16_t* WqkvT  = (bf16_t*)carve((size_t)1536 * 512 * 2);
  bf16_t* GqkvT  = (bf16_t*)carve((size_t)1536 * 128 * 2);
  bf16_t* WoT    = (bf16_t*)carve((size_t)512 * 512 * 2);
  bf16_t* OpT    = (bf16_t*)carve((size_t)512 * 512 * 2);
  float*  bqkv   = (float*)carve(1536 * 4);
  float*  gqkvb  = (float*)carve(1536 * 4);
  float*  dcoef  = (float*)carve(32 * 4);
  float*  dlut   = (float*)carve(4096 * 4);
  bf16_t* QKV    = (bf16_t*)carve((size_t)M_ * 1536 * 2);
  bf16_t* GQKV   = (bf16_t*)carve((size_t)M_ * 1536 * 2);
  bf16_t* Vt     = (bf16_t*)carve((size_t)B_ * 512 * 1024 * 2);
  bf16_t* GVt    = (bf16_t*)carve((size_t)B_ * 512 * 1024 * 2);
  float*  gsc    = (float*)carve((size_t)M_ * 1024 * 4);
  bf16_t* gattn  = (bf16_t*)carve((size_t)M_ * 1024 * 2);
  bf16_t* fatt   = (bf16_t*)carve((size_t)M_ * 512 * 2);
  float*  combF  = (float*)carve((size_t)M_ * 512 * 4);
  bf16_t* combB  = (bf16_t*)carve((size_t)M_ * 512 * 2);
  if (off > ws_size) return;

  dim3 tb(32, 8);
  k_cast_bf16<<<(M_ * F_ / 4 + 255) / 256, 256, 0, stream>>>(features, featBF, M_ * F_ / 4);
  k_cast_bf16<<<(M_ * 128 / 4 + 255) / 256, 256, 0, stream>>>(geometry, geomBF, M_ * 128 / 4);
  k_transpose_w<<<dim3(16, 16), tb, 0, stream>>>(wq, WqkvT, 512, 512);
  k_transpose_w<<<dim3(16, 16), tb, 0, stream>>>(wk, WqkvT + 512 * 512, 512, 512);
  k_transpose_w<<<dim3(16, 16), tb, 0, stream>>>(wv, WqkvT + 1024 * 512, 512, 512);
  k_transpose_w<<<dim3(16, 4), tb, 0, stream>>>(gq_w, GqkvT, 128, 512);
  k_transpose_w<<<dim3(16, 4), tb, 0, stream>>>(gk_w, GqkvT + 512 * 128, 128, 512);
  k_transpose_w<<<dim3(16, 4), tb, 0, stream>>>(gv_w, GqkvT + 1024 * 128, 128, 512);
  k_transpose_w<<<dim3(16, 16), tb, 0, stream>>>(wo, WoT, 512, 512);
  k_transpose_w<<<dim3(16, 16), tb, 0, stream>>>(op_w, OpT, 512, 512);
  k_concat3<<<6, 256, 0, stream>>>(bq, bk, bv, bqkv);
  k_concat3<<<6, 256, 0, stream>>>(gq_b, gk_b, gv_b, gqkvb);
  k_dcoef<<<1, 64, 0, stream>>>(d1_w, d1_b, d2_w, d2_b, dcoef);
  k_build_lut<<<16, 256, 0, stream>>>(dcoef, dlut);

  auto mk = [](const bf16_t* A, long sAb, int lda, const bf16_t* Bt, long sBb, int ldb,
               int K, const float* bias, const float* addSrc, float* outF, bf16_t* outB,
               int ldout, float scale, const float* coords, const float* lut) {
    GemmArgs g;
    g.A = A; g.Bt = Bt; g.bias = bias; g.addSrc = addSrc;
    g.coords = coords; g.lut = lut; g.outF = outF; g.outB = outB;
    g.strideAb = sAb; g.strideBb = sBb; g.lda = lda; g.ldb = ldb;
    g.K = K; g.ldout = ldout; g.scale = scale;
    return g;
  };

  // 1) QKV = features @ [wq|wk|wv] + b
  k_gemm128<0><<<dim3(12, 64), 256, 0, stream>>>(
      mk(featBF, (long)1024 * 512, 512, WqkvT, 0, 512, 512,
         bqkv, nullptr, nullptr, QKV, 1536, 1.f, nullptr, nullptr));
  // 2) GQKV = geometry @ [gq|gk|gv] + b
  k_gemm128<0><<<dim3(12, 64), 256, 0, stream>>>(
      mk(geomBF, (long)1024 * 128, 128, GqkvT, 0, 128, 128,
         gqkvb, nullptr, nullptr, GQKV, 1536, 1.f, nullptr, nullptr));
  // 3) V, GV -> (B, 512, N)
  k_transpose_v<<<dim3(16, 32, 8), tb, 0, stream>>>(QKV, Vt, 1536, 1024);
  k_transpose_v<<<dim3(16, 32, 8), tb, 0, stream>>>(GQKV, GVt, 1536, 1024);
  // 4) g-scores = GQ.GK^T/8 + LUT(dist)
  k_gemm128<1><<<dim3(8, 64), 256, 0, stream>>>(
      mk(GQKV, (long)1024 * 1536, 1536, GQKV + 512, (long)1024 * 1536, 1536, 512,
         nullptr, nullptr, gsc, nullptr, 1024, 0.125f, coords, dlut));
  // 5) g_attn = softmax(g-scores)
  k_softmax_rows<<<8192, 256, 0, stream>>>(gsc, gattn);
  // 6) feature flash attention (block-shared LDS K/V)
  k_flash_feat<<<dim3(16, 64), 256, 0, stream>>>(QKV, Vt, fatt);
  // 7) combF = fatt @ wo + bo
  k_gemm128<0><<<dim3(4, 64), 256, 0, stream>>>(
      mk(fatt, (long)1024 * 512, 512, WoT, 0, 512, 512,
         bo, nullptr, combF, nullptr, 512, 1.f, nullptr, nullptr));
  // 8) combB = combF + g_attn @ GV
  k_gemm128<0><<<dim3(4, 64), 256, 0, stream>>>(
      mk(gattn, (long)1024 * 1024, 1024, GVt, (long)512 * 1024, 1024, 1024,
         nullptr, combF, nullptr, combB, 512, 1.f, nullptr, nullptr));
  // 9) out = combB @ op_w + op_b
  k_gemm128<0><<<dim3(4, 64), 256, 0, stream>>>(
      mk(combB, (long)1024 * 512, 512, OpT, 0, 512, 512,
         op_b, nullptr, (float*)d_out, nullptr, 512, 1.f, nullptr, nullptr));
}

// Round 6
// 230.974 us; speedup vs baseline: 1.2160x; 1.0625x over previous
//
#include <hip/hip_runtime.h>

typedef __bf16 bf16_t;
typedef __bf16 bf16x8 __attribute__((ext_vector_type(8)));
typedef __bf16 bf16x4v __attribute__((ext_vector_type(4)));
typedef float f32x4 __attribute__((ext_vector_type(4)));

#define MFMA16(a, b, c) __builtin_amdgcn_mfma_f32_16x16x32_bf16((a), (b), (c), 0, 0, 0)

// problem constants
static constexpr int B_ = 8, N_ = 1024, F_ = 512, H_ = 8;
static constexpr int M_ = B_ * N_;  // 8192

__device__ __forceinline__ void gl_lds16(const bf16_t* gsrc, bf16_t* ldst) {
  // async global->LDS, 16B/lane; LDS dest = wave-uniform base + lane*16
  __builtin_amdgcn_global_load_lds(
      (const __attribute__((address_space(1))) void*)gsrc,
      (__attribute__((address_space(3))) void*)ldst, 16, 0, 0);
}

// ---------------- prep kernels ----------------
__global__ __launch_bounds__(256) void k_cast_bf16(const float* __restrict__ in,
                                                   bf16_t* __restrict__ out, int n4) {
  int i = blockIdx.x * 256 + threadIdx.x;
  if (i >= n4) return;
  float4 v = ((const float4*)in)[i];
  bf16x4v o;
  o[0] = (bf16_t)v.x; o[1] = (bf16_t)v.y; o[2] = (bf16_t)v.z; o[3] = (bf16_t)v.w;
  ((bf16x4v*)out)[i] = o;
}

// W (K,N) f32 row-major -> Wt (N,K) bf16
__global__ void k_transpose_w(const float* __restrict__ W, bf16_t* __restrict__ Wt,
                              int K, int N) {
  __shared__ float t[32][33];
  int kb = blockIdx.y * 32, cb = blockIdx.x * 32;
  int tx = threadIdx.x, ty = threadIdx.y;  // (32,8)
#pragma unroll
  for (int i = 0; i < 4; ++i)
    t[ty * 4 + i][tx] = W[(long)(kb + ty * 4 + i) * N + cb + tx];
  __syncthreads();
#pragma unroll
  for (int i = 0; i < 4; ++i)
    Wt[(long)(cb + ty * 4 + i) * K + kb + tx] = (bf16_t)t[tx][ty * 4 + i];
}

// per b: in[(b*1024+n)*inStride + colOff + c] (c<512) -> out[(b*512+c)*1024 + n]
__global__ void k_transpose_v(const bf16_t* __restrict__ in, bf16_t* __restrict__ out,
                              int inStride, int colOff) {
  __shared__ bf16_t t[32][33];
  int b = blockIdx.z;
  int cb = blockIdx.x * 32, nb = blockIdx.y * 32;
  int tx = threadIdx.x, ty = threadIdx.y;  // (32,8)
#pragma unroll
  for (int i = 0; i < 4; ++i)
    t[ty * 4 + i][tx] = in[((long)b * 1024 + nb + ty * 4 + i) * inStride + colOff + cb + tx];
  __syncthreads();
#pragma unroll
  for (int i = 0; i < 4; ++i)
    out[((long)b * 512 + cb + ty * 4 + i) * 1024 + nb + tx] = t[tx][ty * 4 + i];
}

__global__ void k_concat3(const float* a, const float* b, const float* c, float* dst) {
  int i = blockIdx.x * 256 + threadIdx.x;
  if (i >= 1536) return;
  dst[i] = i < 512 ? a[i] : (i < 1024 ? b[i - 512] : c[i - 1024]);
}

// reduce dist-MLP to 8 gelu coeffs: meanDW(d) = dc[24] + sum_j gelu(d*dc[j]+dc[8+j])*dc[16+j]
__global__ void k_dcoef(const float* d1w, const float* d1b, const float* d2w,
                        const float* d2b, float* dc) {
  int j = threadIdx.x;
  if (j < 8) {
    dc[j] = d1w[j];
    dc[8 + j] = d1b[j];
    float s = 0.f;
    for (int h = 0; h < 8; ++h) s += d2w[j * 8 + h];
    dc[16 + j] = s * 0.125f;
  }
  if (j == 0) {
    float s = 0.f;
    for (int h = 0; h < 8; ++h) s += d2b[h];
    dc[24] = s * 0.125f;
  }
}

__device__ __forceinline__ float gelu_tanh(float u) {
  // jax.nn.gelu approximate=True
  float g = 0.7978845608028654f * fmaf(0.044715f * u * u, u, u);
  float e = __expf(2.f * g);
  float t = 1.f - 2.f / (e + 1.f);
  return 0.5f * u * (1.f + t);
}

// LUT over d in [0,16), 4096 bins, value at bin center
__global__ void k_build_lut(const float* __restrict__ dc, float* __restrict__ lut) {
  int i = blockIdx.x * 256 + threadIdx.x;
  if (i >= 4096) return;
  float d = (i + 0.5f) * (16.f / 4096.f);
  float s = dc[24];
#pragma unroll
  for (int j = 0; j < 8; ++j)
    s = fmaf(gelu_tanh(fmaf(d, dc[j], dc[8 + j])), dc[16 + j], s);
  lut[i] = s;
}

// ---------------- 128x128 bf16 GEMM, BK=64, global_load_lds (m97 structure) -----
struct GemmArgs {
  const bf16_t* A; const bf16_t* Bt;
  const float* bias; const float* addSrc;
  const float* coords; const float* lut;
  float* outF; bf16_t* outB;
  long strideAb; long strideBb;
  int lda, ldb, K, ldout;
  float scale;
};

template <int DIST>
__global__ __launch_bounds__(256) void k_gemm128(GemmArgs g) {
  __shared__ alignas(16) bf16_t As[128][64];
  __shared__ alignas(16) bf16_t Bs[128][64];
  __shared__ float Lut[DIST ? 4096 : 4];
  const int tid = threadIdx.x;
  const int w = tid >> 6, lane = tid & 63;
  const int lr = lane & 15, lg = lane >> 4;
  const int wr = w >> 1, wc = w & 1;
  const int mBase = blockIdx.y * 128, cBase = blockIdx.x * 128;
  const int batch = mBase >> 10;  // 128 | 1024, tiles never cross batch

  if constexpr (DIST) {
    const float4* src = (const float4*)g.lut;
    ((float4*)Lut)[tid] = src[tid];
    ((float4*)Lut)[tid + 256] = src[tid + 256];
    ((float4*)Lut)[tid + 512] = src[tid + 512];
    ((float4*)Lut)[tid + 768] = src[tid + 768];
  }

  // staging: each wave owns 32 rows of As and Bs; 1 issue = 8 rows (64 lanes x 16B)
  const int srow = lane >> 3;           // 0..7
  const int scol = (lane & 7) * 8;      // element offset within row
  const bf16_t* Ag = g.A + (long)batch * g.strideAb +
                     (long)((mBase & 1023) + w * 32 + srow) * g.lda + scol;
  const bf16_t* Bg = g.Bt + (long)batch * g.strideBb +
                     (long)(cBase + w * 32 + srow) * g.ldb + scol;
  bf16_t* Al = &As[w * 32][0];
  bf16_t* Bl = &Bs[w * 32][0];

  f32x4 zero = {0.f, 0.f, 0.f, 0.f};
  f32x4 acc[4][4];
#pragma unroll
  for (int i = 0; i < 4; ++i)
#pragma unroll
    for (int j = 0; j < 4; ++j) acc[i][j] = zero;

  for (int k0 = 0; k0 < g.K; k0 += 64) {
#pragma unroll
    for (int is = 0; is < 4; ++is) {
      gl_lds16(Ag + (long)(is * 8) * g.lda + k0, Al + is * 8 * 64);
      gl_lds16(Bg + (long)(is * 8) * g.ldb + k0, Bl + is * 8 * 64);
    }
    __syncthreads();  // drains vmcnt(0): tile staged
#pragma unroll
    for (int ks = 0; ks < 2; ++ks) {
      bf16x8 a[4], b[4];
#pragma unroll
      for (int i = 0; i < 4; ++i) {
        a[i] = *(const bf16x8*)(&As[wr * 64 + i * 16 + lr][ks * 32 + lg * 8]);
        b[i] = *(const bf16x8*)(&Bs[wc * 64 + i * 16 + lr][ks * 32 + lg * 8]);
      }
#pragma unroll
      for (int mf = 0; mf < 4; ++mf)
#pragma unroll
        for (int nf = 0; nf < 4; ++nf)
          acc[mf][nf] = MFMA16(a[mf], b[nf], acc[mf][nf]);
    }
    __syncthreads();  // all reads done before next overwrite
  }

  // ---- epilogue ----
  const int c0 = cBase + wc * 64;
  float bias4[4];
#pragma unroll
  for (int nf = 0; nf < 4; ++nf)
    bias4[nf] = g.bias ? g.bias[c0 + nf * 16 + lr] : 0.f;
  float ckx[4], cky[4], ckz[4];
  if constexpr (DIST) {
#pragma unroll
    for (int nf = 0; nf < 4; ++nf) {
      const float* ck = g.coords + ((long)batch * 1024 + c0 + nf * 16 + lr) * 3;
      ckx[nf] = ck[0]; cky[nf] = ck[1]; ckz[nf] = ck[2];
    }
  }
#pragma unroll
  for (int mf = 0; mf < 4; ++mf) {
    const int r0 = mBase + wr * 64 + mf * 16 + lg * 4;
    float cqx[4], cqy[4], cqz[4];
    if constexpr (DIST) {
#pragma unroll
      for (int rg = 0; rg < 4; ++rg) {
        const float* cq = g.coords + ((long)batch * 1024 + ((r0 + rg) & 1023)) * 3;
        cqx[rg] = cq[0]; cqy[rg] = cq[1]; cqz[rg] = cq[2];
      }
    }
#pragma unroll
    for (int nf = 0; nf < 4; ++nf) {
      const int c = c0 + nf * 16 + lr;
#pragma unroll
      for (int rg = 0; rg < 4; ++rg) {
        const int r = r0 + rg;
        float v = acc[mf][nf][rg] * g.scale + bias4[nf];
        if (g.addSrc) v += g.addSrc[(long)r * g.ldout + c];
        if constexpr (DIST) {
          float dx = cqx[rg] - ckx[nf], dy = cqy[rg] - cky[nf], dz = cqz[rg] - ckz[nf];
          float d = sqrtf(fmaxf(dx * dx + dy * dy + dz * dz, 1e-12f));
          int idx = (int)(d * 256.f);
          idx = idx > 4095 ? 4095 : idx;
          v += Lut[idx];
        }
        const long oi = (long)r * g.ldout + c;
        if (g.outF) g.outF[oi] = v;
        if (g.outB) g.outB[oi] = (bf16_t)v;
      }
    }
  }
}

// ------------- 128x64 bf16 GEMM (for N=512 outputs: 2 blocks/CU vs 1) ----------
__global__ __launch_bounds__(256) void k_gemm_n64(GemmArgs g) {
  __shared__ alignas(16) bf16_t As[128][64];
  __shared__ alignas(16) bf16_t Bs[64][64];
  const int tid = threadIdx.x;
  const int w = tid >> 6, lane = tid & 63;
  const int lr = lane & 15, lg = lane >> 4;
  const int wr = w >> 1, wc = w & 1;
  const int mBase = blockIdx.y * 128, cBase = blockIdx.x * 64;
  const int batch = mBase >> 10;

  const int srow = lane >> 3;
  const int scol = (lane & 7) * 8;
  const bf16_t* Ag = g.A + (long)batch * g.strideAb +
                     (long)((mBase & 1023) + w * 32 + srow) * g.lda + scol;
  const bf16_t* Bg = g.Bt + (long)batch * g.strideBb +
                     (long)(cBase + w * 16 + srow) * g.ldb + scol;
  bf16_t* Al = &As[w * 32][0];
  bf16_t* Bl = &Bs[w * 16][0];

  f32x4 zero = {0.f, 0.f, 0.f, 0.f};
  f32x4 acc[4][2];
#pragma unroll
  for (int i = 0; i < 4; ++i)
#pragma unroll
    for (int j = 0; j < 2; ++j) acc[i][j] = zero;

  for (int k0 = 0; k0 < g.K; k0 += 64) {
#pragma unroll
    for (int is = 0; is < 4; ++is)
      gl_lds16(Ag + (long)(is * 8) * g.lda + k0, Al + is * 8 * 64);
#pragma unroll
    for (int is = 0; is < 2; ++is)
      gl_lds16(Bg + (long)(is * 8) * g.ldb + k0, Bl + is * 8 * 64);
    __syncthreads();
#pragma unroll
    for (int ks = 0; ks < 2; ++ks) {
      bf16x8 a[4], b[2];
#pragma unroll
      for (int i = 0; i < 4; ++i)
        a[i] = *(const bf16x8*)(&As[wr * 64 + i * 16 + lr][ks * 32 + lg * 8]);
#pragma unroll
      for (int j = 0; j < 2; ++j)
        b[j] = *(const bf16x8*)(&Bs[wc * 32 + j * 16 + lr][ks * 32 + lg * 8]);
#pragma unroll
      for (int mf = 0; mf < 4; ++mf)
#pragma unroll
        for (int nf = 0; nf < 2; ++nf)
          acc[mf][nf] = MFMA16(a[mf], b[nf], acc[mf][nf]);
    }
    __syncthreads();
  }

  const int c0 = cBase + wc * 32;
  float bias2[2];
#pragma unroll
  for (int nf = 0; nf < 2; ++nf)
    bias2[nf] = g.bias ? g.bias[c0 + nf * 16 + lr] : 0.f;
#pragma unroll
  for (int mf = 0; mf < 4; ++mf) {
    const int r0 = mBase + wr * 64 + mf * 16 + lg * 4;
#pragma unroll
    for (int nf = 0; nf < 2; ++nf) {
      const int c = c0 + nf * 16 + lr;
#pragma unroll
      for (int rg = 0; rg < 4; ++rg) {
        const int r = r0 + rg;
        float v = acc[mf][nf][rg] * g.scale + bias2[nf];
        if (g.addSrc) v += g.addSrc[(long)r * g.ldout + c];
        const long oi = (long)r * g.ldout + c;
        if (g.outF) g.outF[oi] = v;
        if (g.outB) g.outB[oi] = (bf16_t)v;
      }
    }
  }
}

// ---------------- row softmax (1024 cols, fp32 in -> bf16 out) ----------------
__global__ __launch_bounds__(256) void k_softmax_rows(const float* __restrict__ S,
                                                      bf16_t* __restrict__ P) {
  const long row = blockIdx.x;
  const float* s = S + row * 1024;
  const int tid = threadIdx.x;
  float4 v = ((const float4*)s)[tid];
  float mx = fmaxf(fmaxf(v.x, v.y), fmaxf(v.z, v.w));
#pragma unroll
  for (int d = 1; d < 64; d <<= 1) mx = fmaxf(mx, __shfl_xor(mx, d));
  __shared__ float redM[4], redS[4];
  if ((tid & 63) == 0) redM[tid >> 6] = mx;
  __syncthreads();
  mx = fmaxf(fmaxf(redM[0], redM[1]), fmaxf(redM[2], redM[3]));
  float e0 = __expf(v.x - mx), e1 = __expf(v.y - mx);
  float e2 = __expf(v.z - mx), e3 = __expf(v.w - mx);
  float sm = e0 + e1 + e2 + e3;
#pragma unroll
  for (int d = 1; d < 64; d <<= 1) sm += __shfl_xor(sm, d);
  if ((tid & 63) == 0) redS[tid >> 6] = sm;
  __syncthreads();
  sm = redS[0] + redS[1] + redS[2] + redS[3];
  float inv = 1.f / sm;
  bf16x4v o;
  o[0] = (bf16_t)(e0 * inv); o[1] = (bf16_t)(e1 * inv);
  o[2] = (bf16_t)(e2 * inv); o[3] = (bf16_t)(e3 * inv);
  ((bf16x4v*)(P + row * 1024))[tid] = o;
}

// -------- feature flash attention: block-shared LDS K/V, XOR-swizzled ----------
// Round-6: Q pre-scaled by 0.125*log2(e) (no per-kk muls); t-loop unrolled x2 so
// the LDS buffer index is compile-time -> all ds addresses become one lane-base
// VGPR + immediate offset (no per-iteration address VALU).
__global__ __launch_bounds__(256) void k_flash_feat(const bf16_t* __restrict__ QKV,
                                                    const bf16_t* __restrict__ Vt,
                                                    bf16_t* __restrict__ fatt) {
  const int wave = threadIdx.x >> 6, lane = threadIdx.x & 63;
  const int lr = lane & 15, lg = (lane >> 4) & 3;
  const int bh = blockIdx.y, b = bh >> 3, h = bh & 7;
  const int qbase = blockIdx.x * 64 + wave * 16;
  __shared__ alignas(16) bf16_t Ks[2][64][64];   // [buf][key][d]
  __shared__ alignas(16) bf16_t Vs[2][64][64];   // [buf][d][key]
  __shared__ alignas(16) bf16_t Pl[4][16][40];   // per-wave P relayout

  const bf16_t* Qb = QKV + (long)b * 1024 * 1536 + h * 64;
  const bf16_t* Kb = Qb + 512;
  const bf16_t* Vg = Vt + ((long)b * 512 + h * 64) * 1024;

  // Q B-frag, PRE-SCALED by SCL = 0.125*log2(e): p = exp2(S) directly.
  constexpr float SCL = 0.18033688011112042f;
  bf16x8 q_[2];
#pragma unroll
  for (int dh = 0; dh < 2; ++dh) {
    bf16x8 raw = *(const bf16x8*)(Qb + (long)(qbase + lr) * 1536 + dh * 32 + lg * 8);
#pragma unroll
    for (int j = 0; j < 8; ++j) q_[dh][j] = (bf16_t)((float)raw[j] * SCL);
  }

  // staging: wave stages rows [wave*16, wave*16+16) of K and V^T tiles.
  // linear LDS dest; source col pre-swizzled (rule #21): LDS[row][c]=data[row][c^((row&7)*8)]
  const int srow = lane >> 3;
  const int scol = (((lane & 7) ^ srow) << 3);
  const bf16_t* KgB = Kb + (long)(wave * 16 + srow) * 1536 + scol;
  const bf16_t* VgB = Vg + (long)(wave * 16 + srow) * 1024 + scol;

  auto stage = [&](int buf, int kt) {
#pragma unroll
    for (int i = 0; i < 2; ++i) {
      gl_lds16(KgB + (long)(kt + i * 8) * 1536, &Ks[buf][wave * 16 + i * 8][0]);
      gl_lds16(VgB + (long)(i * 8) * 1024 + kt, &Vs[buf][wave * 16 + i * 8][0]);
    }
  };

  f32x4 zero = {0.f, 0.f, 0.f, 0.f};
  f32x4 oacc[4] = {zero, zero, zero, zero};
  float lsum0 = 0.f, lsum1 = 0.f;
  const int swz = (lr & 7) << 4;
  char* PlW = (char*)&Pl[wave][0][0];

  stage(0, 0);
  asm volatile("s_waitcnt vmcnt(0)" ::: "memory");
  __syncthreads();

  // buf is a COMPILE-TIME constant at both call sites (t-loop unrolled x2)
  auto tile = [&](const int buf, int t) __attribute__((always_inline)) {
    if (t < 15) stage(buf ^ 1, (t + 1) * 64);
    const char* KB = (const char*)&Ks[buf][0][0];
    const char* VB = (const char*)&Vs[buf][0][0];
#pragma unroll
    for (int kk = 0; kk < 2; ++kk) {
      f32x4 S[2];
      __builtin_amdgcn_s_setprio(1);
#pragma unroll
      for (int kh = 0; kh < 2; ++kh) {
        const int row = kk * 32 + kh * 16 + lr;
        bf16x8 k0 = *(const bf16x8*)(KB + row * 128 + ((lg * 16) ^ swz));
        bf16x8 k1 = *(const bf16x8*)(KB + row * 128 + ((64 + lg * 16) ^ swz));
        f32x4 tt = MFMA16(k0, q_[0], zero);
        S[kh] = MFMA16(k1, q_[1], tt);
      }
      __builtin_amdgcn_s_setprio(0);
#pragma unroll
      for (int kh = 0; kh < 2; ++kh) {
        bf16x4v pp;
#pragma unroll
        for (int r = 0; r < 4; ++r) {
          float e = exp2f(S[kh][r]);
          if (kh) lsum1 += e; else lsum0 += e;
          pp[r] = (bf16_t)e;
        }
        *(bf16x4v*)(PlW + lr * 80 + kh * 32 + lg * 8) = pp;
      }
      asm volatile("s_waitcnt lgkmcnt(0)" ::: "memory");
      const bf16x8 pa = *(const bf16x8*)(PlW + lr * 80 + lg * 16);
      __builtin_amdgcn_s_setprio(1);
#pragma unroll
      for (int ct = 0; ct < 4; ++ct) {
        const int vrow = ct * 16 + lr;
        bf16x8 vf = *(const bf16x8*)(VB + vrow * 128 + ((kk * 64 + lg * 16) ^ swz));
        oacc[ct] = MFMA16(pa, vf, oacc[ct]);
      }
      __builtin_amdgcn_s_setprio(0);
    }
    asm volatile("s_waitcnt vmcnt(0)" ::: "memory");
    __syncthreads();
  };

  for (int tt = 0; tt < 8; ++tt) {
    tile(0, tt * 2);
    tile(1, tt * 2 + 1);
  }

  float lsum = lsum0 + lsum1;
  lsum += __shfl_xor(lsum, 16);
  lsum += __shfl_xor(lsum, 32);
#pragma unroll
  for (int r = 0; r < 4; ++r) {
    float inv = 1.f / __shfl(lsum, lg * 4 + r, 64);
    int q = qbase + lg * 4 + r;
    bf16_t* orow = fatt + ((long)b * 1024 + q) * 512 + h * 64;
#pragma unroll
    for (int ct = 0; ct < 4; ++ct)
      orow[ct * 16 + lr] = (bf16_t)(oacc[ct][r] * inv);
  }
}

// ---------------- launch ----------------
extern "C" void kernel_launch(void* const* d_in, const int* in_sizes, int n_in,
                              void* d_out, int out_size, void* d_ws, size_t ws_size,
                              hipStream_t stream) {
  const float* features = (const float*)d_in[0];
  const float* geometry = (const float*)d_in[1];
  const float* coords   = (const float*)d_in[2];
  const float* wq = (const float*)d_in[3];  const float* bq = (const float*)d_in[4];
  const float* wk = (const float*)d_in[5];  const float* bk = (const float*)d_in[6];
  const float* wv = (const float*)d_in[7];  const float* bv = (const float*)d_in[8];
  const float* wo = (const float*)d_in[9];  const float* bo = (const float*)d_in[10];
  const float* gq_w = (const float*)d_in[11]; const float* gq_b = (const float*)d_in[12];
  const float* gk_w = (const float*)d_in[13]; const float* gk_b = (const float*)d_in[14];
  const float* gv_w = (const float*)d_in[15]; const float* gv_b = (const float*)d_in[16];
  const float* d1_w = (const float*)d_in[17]; const float* d1_b = (const float*)d_in[18];
  const float* d2_w = (const float*)d_in[19]; const float* d2_b = (const float*)d_in[20];
  const float* op_w = (const float*)d_in[21]; const float* op_b = (const float*)d_in[22];

  // ---- workspace carve ----
  size_t off = 0;
  auto carve = [&](size_t bytes) {
    void* p = (char*)d_ws + off;
    off += (bytes + 255) & ~(size_t)255;
    return p;
  };
  bf16_t* featBF = (bf16_t*)carve((size_t)M_ * F_ * 2);
  bf16_t* geomBF = (bf16_t*)carve((size_t)M_ * 128 * 2);
  bf16_t* WqkvT  = (bf16_t*)carve((size_t)1536 * 512 * 2);
  bf16_t* GqkvT  = (bf16_t*)carve((size_t)1536 * 128 * 2);
  bf16_t* WoT    = (bf16_t*)carve((size_t)512 * 512 * 2);
  bf16_t* OpT    = (bf16_t*)carve((size_t)512 * 512 * 2);
  float*  bqkv   = (float*)carve(1536 * 4);
  float*  gqkvb  = (float*)carve(1536 * 4);
  float*  dcoef  = (float*)carve(32 * 4);
  float*  dlut   = (float*)carve(4096 * 4);
  bf16_t* QKV    = (bf16_t*)carve((size_t)M_ * 1536 * 2);
  bf16_t* GQKV   = (bf16_t*)carve((size_t)M_ * 1536 * 2);
  bf16_t* Vt     = (bf16_t*)carve((size_t)B_ * 512 * 1024 * 2);
  bf16_t* GVt    = (bf16_t*)carve((size_t)B_ * 512 * 1024 * 2);
  float*  gsc    = (float*)carve((size_t)M_ * 1024 * 4);
  bf16_t* gattn  = (bf16_t*)carve((size_t)M_ * 1024 * 2);
  bf16_t* fatt   = (bf16_t*)carve((size_t)M_ * 512 * 2);
  float*  combF  = (float*)carve((size_t)M_ * 512 * 4);
  bf16_t* combB  = (bf16_t*)carve((size_t)M_ * 512 * 2);
  if (off > ws_size) return;

  dim3 tb(32, 8);
  k_cast_bf16<<<(M_ * F_ / 4 + 255) / 256, 256, 0, stream>>>(features, featBF, M_ * F_ / 4);
  k_cast_bf16<<<(M_ * 128 / 4 + 255) / 256, 256, 0, stream>>>(geometry, geomBF, M_ * 128 / 4);
  k_transpose_w<<<dim3(16, 16), tb, 0, stream>>>(wq, WqkvT, 512, 512);
  k_transpose_w<<<dim3(16, 16), tb, 0, stream>>>(wk, WqkvT + 512 * 512, 512, 512);
  k_transpose_w<<<dim3(16, 16), tb, 0, stream>>>(wv, WqkvT + 1024 * 512, 512, 512);
  k_transpose_w<<<dim3(16, 4), tb, 0, stream>>>(gq_w, GqkvT, 128, 512);
  k_transpose_w<<<dim3(16, 4), tb, 0, stream>>>(gk_w, GqkvT + 512 * 128, 128, 512);
  k_transpose_w<<<dim3(16, 4), tb, 0, stream>>>(gv_w, GqkvT + 1024 * 128, 128, 512);
  k_transpose_w<<<dim3(16, 16), tb, 0, stream>>>(wo, WoT, 512, 512);
  k_transpose_w<<<dim3(16, 16), tb, 0, stream>>>(op_w, OpT, 512, 512);
  k_concat3<<<6, 256, 0, stream>>>(bq, bk, bv, bqkv);
  k_concat3<<<6, 256, 0, stream>>>(gq_b, gk_b, gv_b, gqkvb);
  k_dcoef<<<1, 64, 0, stream>>>(d1_w, d1_b, d2_w, d2_b, dcoef);
  k_build_lut<<<16, 256, 0, stream>>>(dcoef, dlut);

  auto mk = [](const bf16_t* A, long sAb, int lda, const bf16_t* Bt, long sBb, int ldb,
               int K, const float* bias, const float* addSrc, float* outF, bf16_t* outB,
               int ldout, float scale, const float* coords, const float* lut) {
    GemmArgs g;
    g.A = A; g.Bt = Bt; g.bias = bias; g.addSrc = addSrc;
    g.coords = coords; g.lut = lut; g.outF = outF; g.outB = outB;
    g.strideAb = sAb; g.strideBb = sBb; g.lda = lda; g.ldb = ldb;
    g.K = K; g.ldout = ldout; g.scale = scale;
    return g;
  };

  // 1) QKV = features @ [wq|wk|wv] + b
  k_gemm128<0><<<dim3(12, 64), 256, 0, stream>>>(
      mk(featBF, (long)1024 * 512, 512, WqkvT, 0, 512, 512,
         bqkv, nullptr, nullptr, QKV, 1536, 1.f, nullptr, nullptr));
  // 2) GQKV = geometry @ [gq|gk|gv] + b
  k_gemm128<0><<<dim3(12, 64), 256, 0, stream>>>(
      mk(geomBF, (long)1024 * 128, 128, GqkvT, 0, 128, 128,
         gqkvb, nullptr, nullptr, GQKV, 1536, 1.f, nullptr, nullptr));
  // 3) V, GV -> (B, 512, N)
  k_transpose_v<<<dim3(16, 32, 8), tb, 0, stream>>>(QKV, Vt, 1536, 1024);
  k_transpose_v<<<dim3(16, 32, 8), tb, 0, stream>>>(GQKV, GVt, 1536, 1024);
  // 4) g-scores = GQ.GK^T/8 + LUT(dist)
  k_gemm128<1><<<dim3(8, 64), 256, 0, stream>>>(
      mk(GQKV, (long)1024 * 1536, 1536, GQKV + 512, (long)1024 * 1536, 1536, 512,
         nullptr, nullptr, gsc, nullptr, 1024, 0.125f, coords, dlut));
  // 5) g_attn = softmax(g-scores)
  k_softmax_rows<<<8192, 256, 0, stream>>>(gsc, gattn);
  // 6) feature flash attention (block-shared LDS K/V)
  k_flash_feat<<<dim3(16, 64), 256, 0, stream>>>(QKV, Vt, fatt);
  // 7) combF = fatt @ wo + bo   (128x64 tile: 2 blocks/CU)
  k_gemm_n64<<<dim3(8, 64), 256, 0, stream>>>(
      mk(fatt, (long)1024 * 512, 512, WoT, 0, 512, 512,
         bo, nullptr, combF, nullptr, 512, 1.f, nullptr, nullptr));
  // 8) combB = combF + g_attn @ GV
  k_gemm_n64<<<dim3(8, 64), 256, 0, stream>>>(
      mk(gattn, (long)1024 * 1024, 1024, GVt, (long)512 * 1024, 1024, 1024,
         nullptr, combF, nullptr, combB, 512, 1.f, nullptr, nullptr));
  // 9) out = combB @ op_w + op_b
  k_gemm_n64<<<dim3(8, 64), 256, 0, stream>>>(
      mk(combB, (long)1024 * 512, 512, OpT, 0, 512, 512,
         op_b, nullptr, (float*)d_out, nullptr, 512, 1.f, nullptr, nullptr));
}